// Round 5
// baseline (93.898 us; speedup 1.0000x reference)
//
#include <hip/hip_runtime.h>
#include <hip/hip_bf16.h>

// Radon transform: x (4,1,384,384) f32 -> out (4,460,64) f32
// pad = 38, Hp = Wp = 460, N_ANGLES = 64.
//
// R5: R4 mapping (wave = 4 y x 4 batches, 16-lane groups over xx) + bf16
// staged images so pb+pbT = 2.5 MB fits one XCD's 4 MiB L2 (R4 thrashed:
// FETCH 27 MB). Bilinear pairs load as one unaligned dword (2 bf16) per
// stencil row -> 8 loads/iter. Tiled-transpose pad kernel (coalesced writes).

constexpr int IMG = 384;
constexpr int PAD = 38;
constexpr int P   = 460;   // Hp = Wp
constexpr int NA  = 64;
constexpr int NB  = 4;
constexpr int B_  = 6;               // zero border
constexpr int O_  = PAD - B_;        // 32
constexpr int E_  = IMG + 2 * B_;    // 396

__device__ __forceinline__ unsigned short f2bf(float f) {
    __hip_bfloat16 h = __float2bfloat16(f);   // RNE
    return __builtin_bit_cast(unsigned short, h);
}
__device__ __forceinline__ float bf_lo(unsigned int w) { return __uint_as_float(w << 16); }
__device__ __forceinline__ float bf_hi(unsigned int w) { return __uint_as_float(w & 0xffff0000u); }

// Tiled pad+transpose: grid (ceil(E/64), ceil(E/64), NB), block (64,4).
__global__ __launch_bounds__(256) void pad2_kernel(const float* __restrict__ x,
                                                   unsigned short* __restrict__ pb,
                                                   unsigned short* __restrict__ pbT) {
    __shared__ float tile[64][65];
    const int tx = threadIdx.x;          // 0..63
    const int ty = threadIdx.y;          // 0..3
    const int bx = blockIdx.x * 64;
    const int by = blockIdx.y * 64;
    const int b  = blockIdx.z;

    for (int r = ty; r < 64; r += 4) {
        const int iy = by + r, ix = bx + tx;
        const int py = iy - B_, px = ix - B_;       // core coords
        float v = 0.0f;
        if ((unsigned)py < (unsigned)IMG && (unsigned)px < (unsigned)IMG)
            v = x[(b * IMG + py) * IMG + px];
        tile[r][tx] = v;
        if (iy < E_ && ix < E_)
            pb[(b * E_ + iy) * E_ + ix] = f2bf(v);
    }
    __syncthreads();
    for (int r = ty; r < 64; r += 4) {
        const int oy = bx + r;           // transposed row = original col
        const int ox = by + tx;
        if (oy < E_ && ox < E_)
            pbT[(b * E_ + oy) * E_ + ox] = f2bf(tile[tx][r]);
    }
}

__global__ __launch_bounds__(256) void radon_kernel(const unsigned short* __restrict__ pb,
                                                    const unsigned short* __restrict__ pbT,
                                                    float* __restrict__ out) {
    const int lane = threadIdx.x & 63;
    const int wv   = threadIdx.x >> 6;
    const int l    = lane & 15;              // lane in group
    const int g    = lane >> 4;              // y-group in wave
    const int a    = blockIdx.y;
    const int y    = blockIdx.x * 16 + wv * 4 + g;

    const float th = (2.8125f * (float)a) * 0.017453292519943295f;
    float s, c;
    __sincosf(th, &s, &c);

    const float yf = (float)(y < P ? y : P - 1);
    const float ys = (2.0f * yf + 1.0f) / 460.0f - 1.0f;
    // fix = c*xx + A ; fiy = s*xx + By (padded-image pixel coords)
    const float A  = fmaf(-s, ys, 1.0f) * 230.0f - 0.5f - 229.5f * c;
    const float By = fmaf( c, ys, 1.0f) * 230.0f - 0.5f - 229.5f * s;

    // xx-interval where the stencil can touch the core ([36,424] conservative;
    // rcp error + floor slack covered by +/-2 and the 6px border).
    const float rc = __builtin_amdgcn_rcpf(c);
    const float rs = __builtin_amdgcn_rcpf(s);
    float t0 = (36.0f - A) * rc, t1 = (424.0f - A) * rc;
    float lo = fmaxf(0.0f,   fminf(t0, t1));
    float hi = fminf(459.0f, fmaxf(t0, t1));
    t0 = (36.0f - By) * rs; t1 = (424.0f - By) * rs;
    lo = fmaxf(lo, fminf(t0, t1));
    hi = fminf(hi, fmaxf(t0, t1));

    int glo = max(0, (int)floorf(lo) - 2);
    glo = min(glo, P);                       // saturate +inf case, avoid wrap
    int ghi = min(P - 1, (int)ceilf(hi) + 2);
    if (y >= P) { glo = 1; ghi = 0; }

    // Layout: row coord v should step slowly with xx -> |cv| = min(|c|,|s|).
    const bool  useT = fabsf(s) > fabsf(c);
    const float cu = useT ? s  : c;
    const float Au = useT ? By : A;
    const float cv = useT ? c  : s;
    const float Av = useT ? A  : By;
    const unsigned short* __restrict__ base = useT ? pbT : pb;
    const unsigned short* __restrict__ i0 = base;
    const unsigned short* __restrict__ i1 = base + 1 * E_ * E_;
    const unsigned short* __restrict__ i2 = base + 2 * E_ * E_;
    const unsigned short* __restrict__ i3 = base + 3 * E_ * E_;

    float acc0 = 0.0f, acc1 = 0.0f, acc2 = 0.0f, acc3 = 0.0f;
    float xxf = (float)(glo + l);
    #pragma unroll 2
    for (int xx = glo + l; xx <= ghi; xx += 16, xxf += 16.0f) {
        const float u   = fmaf(cu, xxf, Au);
        const float v   = fmaf(cv, xxf, Av);
        const float u0f = floorf(u);
        const float v0f = floorf(v);
        const float wu  = u - u0f;
        const float wvv = v - v0f;
        const int idx = (int)fmaf(v0f, (float)E_, u0f) - (O_ * E_ + O_);

        unsigned int w0t, w0b, w1t, w1b, w2t, w2b, w3t, w3b;
        __builtin_memcpy(&w0t, i0 + idx,      4);
        __builtin_memcpy(&w0b, i0 + idx + E_, 4);
        __builtin_memcpy(&w1t, i1 + idx,      4);
        __builtin_memcpy(&w1b, i1 + idx + E_, 4);
        __builtin_memcpy(&w2t, i2 + idx,      4);
        __builtin_memcpy(&w2b, i2 + idx + E_, 4);
        __builtin_memcpy(&w3t, i3 + idx,      4);
        __builtin_memcpy(&w3b, i3 + idx + E_, 4);

        {
            const float top = fmaf(wu, bf_hi(w0t) - bf_lo(w0t), bf_lo(w0t));
            const float bot = fmaf(wu, bf_hi(w0b) - bf_lo(w0b), bf_lo(w0b));
            acc0 += fmaf(wvv, bot - top, top);
        }
        {
            const float top = fmaf(wu, bf_hi(w1t) - bf_lo(w1t), bf_lo(w1t));
            const float bot = fmaf(wu, bf_hi(w1b) - bf_lo(w1b), bf_lo(w1b));
            acc1 += fmaf(wvv, bot - top, top);
        }
        {
            const float top = fmaf(wu, bf_hi(w2t) - bf_lo(w2t), bf_lo(w2t));
            const float bot = fmaf(wu, bf_hi(w2b) - bf_lo(w2b), bf_lo(w2b));
            acc2 += fmaf(wvv, bot - top, top);
        }
        {
            const float top = fmaf(wu, bf_hi(w3t) - bf_lo(w3t), bf_lo(w3t));
            const float bot = fmaf(wu, bf_hi(w3b) - bf_lo(w3b), bf_lo(w3b));
            acc3 += fmaf(wvv, bot - top, top);
        }
    }

    // 4-step butterfly within each 16-lane group; 4 independent chains (ILP)
    #pragma unroll
    for (int m = 1; m <= 8; m <<= 1) {
        acc0 += __shfl_xor(acc0, m);
        acc1 += __shfl_xor(acc1, m);
        acc2 += __shfl_xor(acc2, m);
        acc3 += __shfl_xor(acc3, m);
    }

    if (l == 0 && y < P) {
        out[(0 * P + y) * NA + a] = acc0 / 460.0f;
        out[(1 * P + y) * NA + a] = acc1 / 460.0f;
        out[(2 * P + y) * NA + a] = acc2 / 460.0f;
        out[(3 * P + y) * NA + a] = acc3 / 460.0f;
    }
}

// ---- Fallback (no/undersized workspace): bounds-checked direct sampling ----
__device__ __forceinline__ float samp(const float* __restrict__ img, int iy, int ix) {
    unsigned uy = (unsigned)(iy - PAD);
    unsigned ux = (unsigned)(ix - PAD);
    return (uy < (unsigned)IMG && ux < (unsigned)IMG) ? img[uy * IMG + ux] : 0.0f;
}

__global__ __launch_bounds__(256) void radon_fallback(const float* __restrict__ x,
                                                      float* __restrict__ out) {
    const int wid  = blockIdx.x * 4 + (threadIdx.x >> 6);
    const int lane = threadIdx.x & 63;
    if (wid >= NB * NA * P) return;
    const int y  = wid % P;
    const int ba = wid / P;
    const int a  = ba % NA;
    const int b  = ba / NA;
    const float th = (2.8125f * (float)a) * 0.017453292519943295f;
    float s, c;
    __sincosf(th, &s, &c);
    const float ysy = (2.0f * (float)y + 1.0f) / 460.0f - 1.0f;
    const float* img = x + b * IMG * IMG;
    float acc = 0.0f;
    for (int xx = lane; xx < P; xx += 64) {
        const float xsx = (2.0f * (float)xx + 1.0f) / 460.0f - 1.0f;
        const float gx = c * xsx - s * ysy;
        const float gy = s * xsx + c * ysy;
        const float fix = ((gx + 1.0f) * 460.0f - 1.0f) * 0.5f;
        const float fiy = ((gy + 1.0f) * 460.0f - 1.0f) * 0.5f;
        const float ix0f = floorf(fix);
        const float iy0f = floorf(fiy);
        const float wx = fix - ix0f;
        const float wy = fiy - iy0f;
        const int ix0 = (int)ix0f;
        const int iy0 = (int)iy0f;
        const float v00 = samp(img, iy0,     ix0);
        const float v01 = samp(img, iy0,     ix0 + 1);
        const float v10 = samp(img, iy0 + 1, ix0);
        const float v11 = samp(img, iy0 + 1, ix0 + 1);
        acc += v00 * ((1.0f - wy) * (1.0f - wx))
             + v01 * ((1.0f - wy) * wx)
             + v10 * (wy * (1.0f - wx))
             + v11 * (wy * wx);
    }
    #pragma unroll
    for (int off = 32; off; off >>= 1) acc += __shfl_xor(acc, off);
    if (lane == 0) out[(b * P + y) * NA + a] = acc / 460.0f;
}

extern "C" void kernel_launch(void* const* d_in, const int* in_sizes, int n_in,
                              void* d_out, int out_size, void* d_ws, size_t ws_size,
                              hipStream_t stream) {
    const float* x = (const float*)d_in[0];
    float* out = (float*)d_out;

    const size_t buf_elems = (size_t)NB * E_ * E_;
    const size_t need = 2 * buf_elems * sizeof(unsigned short);

    if (ws_size >= need) {
        unsigned short* pb  = (unsigned short*)d_ws;
        unsigned short* pbT = pb + buf_elems;
        dim3 pgrid((E_ + 63) / 64, (E_ + 63) / 64, NB);   // (7,7,4)
        pad2_kernel<<<pgrid, dim3(64, 4), 0, stream>>>(x, pb, pbT);
        dim3 grid((P + 15) / 16, NA, 1);                  // (29, 64)
        radon_kernel<<<grid, 256, 0, stream>>>(pb, pbT, out);
    } else {
        const int total_waves = NB * NA * P;
        const int blocks = (total_waves + 3) / 4;
        radon_fallback<<<blocks, 256, 0, stream>>>(x, out);
    }
}

// Round 6
// 32.210 us; speedup vs baseline: 2.9152x; 2.9152x over previous
//
#include <hip/hip_runtime.h>
#include <hip/hip_bf16.h>

// Radon transform: x (4,1,384,384) f32 -> out (4,460,64) f32
// pad = 38, Hp = Wp = 460, N_ANGLES = 64.
//
// R6: batch-interleaved bf16 texels. Staged image texel[v][u] holds all 4
// batches as 4x bf16 = 8B (uint2). One aligned dwordx2 load per bilinear
// corner serves 4 batches -> 4 loads/iter (R4: 16 f32 loads; R5: 8 split
// misaligned loads). Footprint: normal + transposed layouts = 2.5 MB total,
// fits one XCD L2. Wave = 4 y (16-lane groups over xx) x 4 batches; per-lane
// interval clip; layout chosen per angle so row coord steps by min(|c|,|s|).

constexpr int IMG = 384;
constexpr int PAD = 38;
constexpr int P   = 460;   // Hp = Wp
constexpr int NA  = 64;
constexpr int NB  = 4;
constexpr int B_  = 6;               // zero border
constexpr int O_  = PAD - B_;        // 32
constexpr int E_  = IMG + 2 * B_;    // 396

__device__ __forceinline__ unsigned int f2bfu(float f) {
    __hip_bfloat16 h = __float2bfloat16(f);   // RNE
    return (unsigned int)__builtin_bit_cast(unsigned short, h);
}
__device__ __forceinline__ float bf_lo(unsigned int w) { return __uint_as_float(w << 16); }
__device__ __forceinline__ float bf_hi(unsigned int w) { return __uint_as_float(w & 0xffff0000u); }

// Pad + interleave batches + build normal and transposed layouts.
// grid (ceil(E/64), ceil(E/64)), block (64,4). LDS tile for coalesced pbT.
__global__ __launch_bounds__(256) void pad4_kernel(const float* __restrict__ x,
                                                   uint2* __restrict__ pb,
                                                   uint2* __restrict__ pbT) {
    __shared__ uint2 tile[64][65];
    const int tx = threadIdx.x;          // 0..63
    const int ty = threadIdx.y;          // 0..3
    const int bx = blockIdx.x * 64;
    const int by = blockIdx.y * 64;

    for (int r = ty; r < 64; r += 4) {
        const int iy = by + r, ix = bx + tx;
        const int py = iy - B_, px = ix - B_;       // core coords
        uint2 t = make_uint2(0u, 0u);
        if ((unsigned)py < (unsigned)IMG && (unsigned)px < (unsigned)IMG) {
            const int o = py * IMG + px;
            t.x = f2bfu(x[o])                 | (f2bfu(x[IMG * IMG + o])     << 16);
            t.y = f2bfu(x[2 * IMG * IMG + o]) | (f2bfu(x[3 * IMG * IMG + o]) << 16);
        }
        tile[r][tx] = t;
        if (iy < E_ && ix < E_) pb[iy * E_ + ix] = t;
    }
    __syncthreads();
    for (int r = ty; r < 64; r += 4) {
        const int oy = bx + r;           // transposed row = original col
        const int ox = by + tx;
        if (oy < E_ && ox < E_) pbT[oy * E_ + ox] = tile[tx][r];
    }
}

__global__ __launch_bounds__(256) void radon_kernel(const uint2* __restrict__ pb,
                                                    const uint2* __restrict__ pbT,
                                                    float* __restrict__ out) {
    const int lane = threadIdx.x & 63;
    const int wv   = threadIdx.x >> 6;
    const int l    = lane & 15;              // lane in group
    const int g    = lane >> 4;              // y-group in wave
    const int a    = blockIdx.y;
    const int y    = blockIdx.x * 16 + wv * 4 + g;

    const float th = (2.8125f * (float)a) * 0.017453292519943295f;
    float s, c;
    __sincosf(th, &s, &c);

    const float yf = (float)(y < P ? y : P - 1);
    const float ys = (2.0f * yf + 1.0f) / 460.0f - 1.0f;
    // fix = c*xx + A ; fiy = s*xx + By (padded-image pixel coords)
    const float A  = fmaf(-s, ys, 1.0f) * 230.0f - 0.5f - 229.5f * c;
    const float By = fmaf( c, ys, 1.0f) * 230.0f - 0.5f - 229.5f * s;

    // xx-interval where the stencil can touch the core ([36,424] conservative;
    // rcp error + floor slack covered by +/-2 and the 6px border).
    const float rc = __builtin_amdgcn_rcpf(c);
    const float rs = __builtin_amdgcn_rcpf(s);
    float t0 = (36.0f - A) * rc, t1 = (424.0f - A) * rc;
    float lo = fmaxf(0.0f,   fminf(t0, t1));
    float hi = fminf(459.0f, fmaxf(t0, t1));
    t0 = (36.0f - By) * rs; t1 = (424.0f - By) * rs;
    lo = fmaxf(lo, fminf(t0, t1));
    hi = fminf(hi, fmaxf(t0, t1));

    int glo = max(0, (int)floorf(lo) - 2);
    glo = min(glo, P);                       // saturate +inf case, avoid wrap
    int ghi = min(P - 1, (int)ceilf(hi) + 2);
    if (y >= P) { glo = 1; ghi = 0; }

    // Layout: row coord v should step slowly with xx -> |cv| = min(|c|,|s|).
    const bool  useT = fabsf(s) > fabsf(c);
    const float cu = useT ? s  : c;
    const float Au = useT ? By : A;
    const float cv = useT ? c  : s;
    const float Av = useT ? A  : By;
    const uint2* __restrict__ base = useT ? pbT : pb;

    float acc0 = 0.0f, acc1 = 0.0f, acc2 = 0.0f, acc3 = 0.0f;
    float xxf = (float)(glo + l);
    #pragma unroll 2
    for (int xx = glo + l; xx <= ghi; xx += 16, xxf += 16.0f) {
        const float u   = fmaf(cu, xxf, Au);
        const float v   = fmaf(cv, xxf, Av);
        const float u0f = floorf(u);
        const float v0f = floorf(v);
        const float wu  = u - u0f;
        const float wvv = v - v0f;
        const int idx = (int)fmaf(v0f, (float)E_, u0f) - (O_ * E_ + O_);

        const uint2* p = base + idx;
        const uint2 T00 = p[0];
        const uint2 T01 = p[1];
        const uint2 T10 = p[E_];
        const uint2 T11 = p[E_ + 1];

        {   // batch 0: lo halves of .x
            const float top = fmaf(wu, bf_lo(T01.x) - bf_lo(T00.x), bf_lo(T00.x));
            const float bot = fmaf(wu, bf_lo(T11.x) - bf_lo(T10.x), bf_lo(T10.x));
            acc0 += fmaf(wvv, bot - top, top);
        }
        {   // batch 1: hi halves of .x
            const float top = fmaf(wu, bf_hi(T01.x) - bf_hi(T00.x), bf_hi(T00.x));
            const float bot = fmaf(wu, bf_hi(T11.x) - bf_hi(T10.x), bf_hi(T10.x));
            acc1 += fmaf(wvv, bot - top, top);
        }
        {   // batch 2: lo halves of .y
            const float top = fmaf(wu, bf_lo(T01.y) - bf_lo(T00.y), bf_lo(T00.y));
            const float bot = fmaf(wu, bf_lo(T11.y) - bf_lo(T10.y), bf_lo(T10.y));
            acc2 += fmaf(wvv, bot - top, top);
        }
        {   // batch 3: hi halves of .y
            const float top = fmaf(wu, bf_hi(T01.y) - bf_hi(T00.y), bf_hi(T00.y));
            const float bot = fmaf(wu, bf_hi(T11.y) - bf_hi(T10.y), bf_hi(T10.y));
            acc3 += fmaf(wvv, bot - top, top);
        }
    }

    // 4-step butterfly within each 16-lane group; 4 independent chains (ILP)
    #pragma unroll
    for (int m = 1; m <= 8; m <<= 1) {
        acc0 += __shfl_xor(acc0, m);
        acc1 += __shfl_xor(acc1, m);
        acc2 += __shfl_xor(acc2, m);
        acc3 += __shfl_xor(acc3, m);
    }

    if (l == 0 && y < P) {
        out[(0 * P + y) * NA + a] = acc0 / 460.0f;
        out[(1 * P + y) * NA + a] = acc1 / 460.0f;
        out[(2 * P + y) * NA + a] = acc2 / 460.0f;
        out[(3 * P + y) * NA + a] = acc3 / 460.0f;
    }
}

// ---- Fallback (no/undersized workspace): bounds-checked direct sampling ----
__device__ __forceinline__ float samp(const float* __restrict__ img, int iy, int ix) {
    unsigned uy = (unsigned)(iy - PAD);
    unsigned ux = (unsigned)(ix - PAD);
    return (uy < (unsigned)IMG && ux < (unsigned)IMG) ? img[uy * IMG + ux] : 0.0f;
}

__global__ __launch_bounds__(256) void radon_fallback(const float* __restrict__ x,
                                                      float* __restrict__ out) {
    const int wid  = blockIdx.x * 4 + (threadIdx.x >> 6);
    const int lane = threadIdx.x & 63;
    if (wid >= NB * NA * P) return;
    const int y  = wid % P;
    const int ba = wid / P;
    const int a  = ba % NA;
    const int b  = ba / NA;
    const float th = (2.8125f * (float)a) * 0.017453292519943295f;
    float s, c;
    __sincosf(th, &s, &c);
    const float ysy = (2.0f * (float)y + 1.0f) / 460.0f - 1.0f;
    const float* img = x + b * IMG * IMG;
    float acc = 0.0f;
    for (int xx = lane; xx < P; xx += 64) {
        const float xsx = (2.0f * (float)xx + 1.0f) / 460.0f - 1.0f;
        const float gx = c * xsx - s * ysy;
        const float gy = s * xsx + c * ysy;
        const float fix = ((gx + 1.0f) * 460.0f - 1.0f) * 0.5f;
        const float fiy = ((gy + 1.0f) * 460.0f - 1.0f) * 0.5f;
        const float ix0f = floorf(fix);
        const float iy0f = floorf(fiy);
        const float wx = fix - ix0f;
        const float wy = fiy - iy0f;
        const int ix0 = (int)ix0f;
        const int iy0 = (int)iy0f;
        const float v00 = samp(img, iy0,     ix0);
        const float v01 = samp(img, iy0,     ix0 + 1);
        const float v10 = samp(img, iy0 + 1, ix0);
        const float v11 = samp(img, iy0 + 1, ix0 + 1);
        acc += v00 * ((1.0f - wy) * (1.0f - wx))
             + v01 * ((1.0f - wy) * wx)
             + v10 * (wy * (1.0f - wx))
             + v11 * (wy * wx);
    }
    #pragma unroll
    for (int off = 32; off; off >>= 1) acc += __shfl_xor(acc, off);
    if (lane == 0) out[(b * P + y) * NA + a] = acc / 460.0f;
}

extern "C" void kernel_launch(void* const* d_in, const int* in_sizes, int n_in,
                              void* d_out, int out_size, void* d_ws, size_t ws_size,
                              hipStream_t stream) {
    const float* x = (const float*)d_in[0];
    float* out = (float*)d_out;

    const size_t layer = (size_t)E_ * E_;            // texels per layout
    const size_t need  = 2 * layer * sizeof(uint2);  // ~2.5 MB

    if (ws_size >= need) {
        uint2* pb  = (uint2*)d_ws;
        uint2* pbT = pb + layer;
        dim3 pgrid((E_ + 63) / 64, (E_ + 63) / 64);      // (7,7)
        pad4_kernel<<<pgrid, dim3(64, 4), 0, stream>>>(x, pb, pbT);
        dim3 grid((P + 15) / 16, NA, 1);                 // (29, 64)
        radon_kernel<<<grid, 256, 0, stream>>>(pb, pbT, out);
    } else {
        const int total_waves = NB * NA * P;
        const int blocks = (total_waves + 3) / 4;
        radon_fallback<<<blocks, 256, 0, stream>>>(x, out);
    }
}